// Round 1
// baseline (1539.365 us; speedup 1.0000x reference)
//
#include <hip/hip_runtime.h>
#include <math.h>

// Problem constants (reference: B=4, S=2048, D=1024, fp32)
constexpr int B_ = 4;
constexpr int S_ = 2048;
constexpr int D_ = 1024;
constexpr long BS_ = (long)B_ * S_;     // 8192 rows
constexpr float EPS_ = 1e-5f;

// GEMM tiling: 128x128 tile, BK=16, 256 threads, 8x8 per thread.
constexpr int BM = 128, BN = 128, BK = 16;
constexpr int TSTRIDE = 132; // padded LDS stride: 528B rows stay 16B-aligned,
                             // 4*132 % 32 != 0 -> transpose-stores are <=2-way (free)

// C[m,n] = alpha * sum_k A[m,k] * B[k,n] (+ bias[n])
// A: [M,K] lda=K.  B: TRANS_B ? [N,K] : [K,N].  C: [M,N] ldc=N.
// Batched over blockIdx.z with explicit strides (0 = shared operand).
template<bool TRANS_B, bool HAS_BIAS>
__global__ __launch_bounds__(256)
void gemm_tile(const float* __restrict__ Ag, const float* __restrict__ Bg,
               float* __restrict__ Cg, const float* __restrict__ biasg,
               long batchBias, int K, int N,
               long batchA, long batchB, long batchC, float alpha)
{
    const int bz = blockIdx.z;
    const float* A = Ag + bz * batchA;
    const float* Bp = Bg + bz * batchB;
    float* C = Cg + bz * batchC;

    __shared__ float As[BK][TSTRIDE];
    constexpr int BSTR = TRANS_B ? TSTRIDE : BN;
    __shared__ float Bs[BK][BSTR];

    const int tid = threadIdx.x;
    const int tx = tid & 15;   // 0..15 -> output cols tx*8..+7
    const int ty = tid >> 4;   // 0..15 -> output rows ty*8..+7
    const int row0 = blockIdx.x * BM;
    const int col0 = blockIdx.y * BN;

    float acc[8][8];
#pragma unroll
    for (int i = 0; i < 8; ++i)
#pragma unroll
        for (int j = 0; j < 8; ++j) acc[i][j] = 0.f;

    for (int k0 = 0; k0 < K; k0 += BK) {
        // ---- stage A tile (128 rows x 16 k), store k-major transposed
#pragma unroll
        for (int it = 0; it < 2; ++it) {
            int idx = tid + it * 256;          // 0..511 float4 slots
            int m = idx >> 2;                  // 0..127
            int k4 = (idx & 3) * 4;            // 0,4,8,12
            const float4 v = *(const float4*)(A + (long)(row0 + m) * K + k0 + k4);
            As[k4 + 0][m] = v.x;
            As[k4 + 1][m] = v.y;
            As[k4 + 2][m] = v.z;
            As[k4 + 3][m] = v.w;
        }
        // ---- stage B tile
        if (TRANS_B) {
#pragma unroll
            for (int it = 0; it < 2; ++it) {
                int idx = tid + it * 256;
                int n = idx >> 2;              // 0..127
                int k4 = (idx & 3) * 4;
                const float4 v = *(const float4*)(Bp + (long)(col0 + n) * K + k0 + k4);
                Bs[k4 + 0][n] = v.x;
                Bs[k4 + 1][n] = v.y;
                Bs[k4 + 2][n] = v.z;
                Bs[k4 + 3][n] = v.w;
            }
        } else {
#pragma unroll
            for (int it = 0; it < 2; ++it) {
                int idx = tid + it * 256;
                int kk = idx >> 5;             // 0..15
                int n4 = (idx & 31) * 4;       // 0..124
                const float4 v = *(const float4*)(Bp + (long)(k0 + kk) * N + col0 + n4);
                *(float4*)(&Bs[kk][n4]) = v;
            }
        }
        __syncthreads();

        // ---- 16 k-steps, 64 FMAs each
#pragma unroll
        for (int kk = 0; kk < BK; ++kk) {
            float a[8], b[8];
            *(float4*)(a)     = *(const float4*)(&As[kk][ty * 8]);
            *(float4*)(a + 4) = *(const float4*)(&As[kk][ty * 8 + 4]);
            *(float4*)(b)     = *(const float4*)(&Bs[kk][tx * 8]);
            *(float4*)(b + 4) = *(const float4*)(&Bs[kk][tx * 8 + 4]);
#pragma unroll
            for (int i = 0; i < 8; ++i)
#pragma unroll
                for (int j = 0; j < 8; ++j)
                    acc[i][j] = fmaf(a[i], b[j], acc[i][j]);
        }
        __syncthreads();
    }

    // ---- epilogue: alpha, optional bias, float4 stores
    const float* bias = HAS_BIAS ? (biasg + bz * batchBias) : nullptr;
#pragma unroll
    for (int i = 0; i < 8; ++i) {
        long r = row0 + ty * 8 + i;
#pragma unroll
        for (int j = 0; j < 8; j += 4) {
            int c = col0 + tx * 8 + j;
            float4 v;
            v.x = acc[i][j + 0] * alpha;
            v.y = acc[i][j + 1] * alpha;
            v.z = acc[i][j + 2] * alpha;
            v.w = acc[i][j + 3] * alpha;
            if (HAS_BIAS) {
                v.x += bias[c + 0]; v.y += bias[c + 1];
                v.z += bias[c + 2]; v.w += bias[c + 3];
            }
            *(float4*)(C + r * N + c) = v;
        }
    }
}

// Row softmax over S_=2048 elements, in place. grid = (S_, nbatch)
__global__ __launch_bounds__(256)
void softmax_rows(float* __restrict__ P, long batchStride)
{
    float* row = P + blockIdx.y * batchStride + (long)blockIdx.x * S_;
    const int tid = threadIdx.x;
    const int lane = tid & 63, wid = tid >> 6;
    __shared__ float sm[4], ss[4];

    float4 v0 = ((const float4*)row)[tid];
    float4 v1 = ((const float4*)row)[tid + 256];

    float m = fmaxf(fmaxf(fmaxf(v0.x, v0.y), fmaxf(v0.z, v0.w)),
                    fmaxf(fmaxf(v1.x, v1.y), fmaxf(v1.z, v1.w)));
#pragma unroll
    for (int o = 1; o < 64; o <<= 1) m = fmaxf(m, __shfl_xor(m, o));
    if (lane == 0) sm[wid] = m;
    __syncthreads();
    m = fmaxf(fmaxf(sm[0], sm[1]), fmaxf(sm[2], sm[3]));

    v0.x = expf(v0.x - m); v0.y = expf(v0.y - m);
    v0.z = expf(v0.z - m); v0.w = expf(v0.w - m);
    v1.x = expf(v1.x - m); v1.y = expf(v1.y - m);
    v1.z = expf(v1.z - m); v1.w = expf(v1.w - m);

    float s = v0.x + v0.y + v0.z + v0.w + v1.x + v1.y + v1.z + v1.w;
#pragma unroll
    for (int o = 1; o < 64; o <<= 1) s += __shfl_xor(s, o);
    if (lane == 0) ss[wid] = s;
    __syncthreads();
    s = ss[0] + ss[1] + ss[2] + ss[3];

    const float inv = 1.0f / s;
    v0.x *= inv; v0.y *= inv; v0.z *= inv; v0.w *= inv;
    v1.x *= inv; v1.y *= inv; v1.z *= inv; v1.w *= inv;
    ((float4*)row)[tid] = v0;
    ((float4*)row)[tid + 256] = v1;
}

// h = x + attn; out = LayerNorm(h) * gamma + beta. One block per row.
__global__ __launch_bounds__(256)
void resid_ln(const float* __restrict__ x, const float* __restrict__ attn,
              const float* __restrict__ gamma, const float* __restrict__ beta,
              float* __restrict__ out)
{
    const long row = blockIdx.x;
    const int tid = threadIdx.x;          // D/4 = 256 float4 -> one per thread
    const int lane = tid & 63, wid = tid >> 6;
    __shared__ float s1[4], s2[4];

    float4 xv = ((const float4*)(x + row * D_))[tid];
    float4 av = ((const float4*)(attn + row * D_))[tid];
    float4 h;
    h.x = xv.x + av.x; h.y = xv.y + av.y; h.z = xv.z + av.z; h.w = xv.w + av.w;

    float sum = h.x + h.y + h.z + h.w;
#pragma unroll
    for (int o = 1; o < 64; o <<= 1) sum += __shfl_xor(sum, o);
    if (lane == 0) s1[wid] = sum;
    __syncthreads();
    const float mu = (s1[0] + s1[1] + s1[2] + s1[3]) * (1.0f / D_);

    float dx = h.x - mu, dy = h.y - mu, dz = h.z - mu, dw = h.w - mu;
    float sq = dx * dx + dy * dy + dz * dz + dw * dw;
#pragma unroll
    for (int o = 1; o < 64; o <<= 1) sq += __shfl_xor(sq, o);
    if (lane == 0) s2[wid] = sq;
    __syncthreads();
    const float var = (s2[0] + s2[1] + s2[2] + s2[3]) * (1.0f / D_);
    const float r = rsqrtf(var + EPS_);

    float4 g = ((const float4*)gamma)[tid];
    float4 b = ((const float4*)beta)[tid];
    float4 o4;
    o4.x = dx * r * g.x + b.x;
    o4.y = dy * r * g.y + b.y;
    o4.z = dz * r * g.z + b.z;
    o4.w = dw * r * g.w + b.w;
    ((float4*)(out + row * D_))[tid] = o4;
}

extern "C" void kernel_launch(void* const* d_in, const int* in_sizes, int n_in,
                              void* d_out, int out_size, void* d_ws, size_t ws_size,
                              hipStream_t stream) {
    (void)in_sizes; (void)n_in; (void)out_size;
    const float* x     = (const float*)d_in[0];
    const float* Wq    = (const float*)d_in[1];
    const float* bq    = (const float*)d_in[2];
    const float* Wk    = (const float*)d_in[3];
    const float* bk    = (const float*)d_in[4];
    const float* Wv    = (const float*)d_in[5];
    const float* bv    = (const float*)d_in[6];
    const float* gamma = (const float*)d_in[7];
    const float* beta  = (const float*)d_in[8];
    float* out = (float*)d_out;

    // Workspace layout (bytes):
    //   [0)            QKV: 3 * BS * D floats (Q,K,V contiguous; Q reused as attn_out)
    //   [OFF_W)        Wcat: 3 * D * D floats
    //   [OFF_B)        bcat: 3 * D floats
    //   [OFF_P)        P: full ? 4*S*S : S*S floats
    const size_t SZ_QKV = (size_t)3 * BS_ * D_ * 4;         // 100,663,296
    const size_t SZ_W   = (size_t)3 * D_ * D_ * 4;          //  12,582,912
    const size_t SZ_B   = (size_t)3 * D_ * 4;               //      12,288
    const size_t OFF_W  = SZ_QKV;
    const size_t OFF_B  = OFF_W + SZ_W;
    const size_t OFF_P  = OFF_B + SZ_B;
    const size_t SZ_P1  = (size_t)S_ * S_ * 4;              //  16,777,216
    const bool full = ws_size >= OFF_P + 4 * SZ_P1;         // batched-P path?

    float* qkv  = (float*)d_ws;                 // Q | K | V
    float* wcat = (float*)((char*)d_ws + OFF_W);
    float* bcat = (float*)((char*)d_ws + OFF_B);
    float* P    = (float*)((char*)d_ws + OFF_P);
    float* Q = qkv;
    float* Km = qkv + BS_ * D_;
    float* V = qkv + 2 * BS_ * D_;
    float* O = qkv;                             // attn_out reuses Q's buffer

    // Concatenate weights/biases so QKV projection is one z=3 batched GEMM.
    hipMemcpyAsync(wcat,               Wq, (size_t)D_ * D_ * 4, hipMemcpyDeviceToDevice, stream);
    hipMemcpyAsync(wcat + D_ * D_,     Wk, (size_t)D_ * D_ * 4, hipMemcpyDeviceToDevice, stream);
    hipMemcpyAsync(wcat + 2 * D_ * D_, Wv, (size_t)D_ * D_ * 4, hipMemcpyDeviceToDevice, stream);
    hipMemcpyAsync(bcat,          bq, (size_t)D_ * 4, hipMemcpyDeviceToDevice, stream);
    hipMemcpyAsync(bcat + D_,     bk, (size_t)D_ * 4, hipMemcpyDeviceToDevice, stream);
    hipMemcpyAsync(bcat + 2 * D_, bv, (size_t)D_ * 4, hipMemcpyDeviceToDevice, stream);

    // 1) QKV projections: [8192,1024] @ [1024,1024] + bias, z = {q,k,v}
    gemm_tile<false, true><<<dim3(BS_ / BM, D_ / BN, 3), 256, 0, stream>>>(
        x, wcat, qkv, bcat, (long)D_, D_, D_,
        0L, (long)D_ * D_, BS_ * (long)D_, 1.0f);

    // 2) per-batch attention (z-batched when ws allows)
    const int chunk = full ? 4 : 1;
    const long pstride = full ? (long)S_ * S_ : 0L;
    const long sd = (long)S_ * D_;
    const float alpha = 1.0f / 32.0f;           // 1/sqrt(1024)
    for (int b0 = 0; b0 < B_; b0 += chunk) {
        const float* Qb = Q + b0 * sd;
        const float* Kb = Km + b0 * sd;
        const float* Vb = V + b0 * sd;
        float* Ob = O + b0 * sd;
        // scores = Q @ K^T / 32 : [2048,2048]
        gemm_tile<true, false><<<dim3(S_ / BM, S_ / BN, chunk), 256, 0, stream>>>(
            Qb, Kb, P, nullptr, 0L, D_, S_, sd, sd, pstride, alpha);
        // softmax rows in place
        softmax_rows<<<dim3(S_, chunk), 256, 0, stream>>>(P, pstride);
        // attn_out = P @ V : [2048,1024] (overwrites Q's storage)
        gemm_tile<false, false><<<dim3(S_ / BM, D_ / BN, chunk), 256, 0, stream>>>(
            P, Vb, Ob, nullptr, 0L, S_, D_, pstride, sd, sd, 1.0f);
    }

    // 3) residual + LayerNorm
    resid_ln<<<dim3((int)BS_), 256, 0, stream>>>(x, O, gamma, beta, out);
}

// Round 2
// 336.538 us; speedup vs baseline: 4.5741x; 4.5741x over previous
//
#include <hip/hip_runtime.h>
#include <math.h>

// Problem constants: B=4, S=2048, D=1024, fp32 in/out
constexpr int B_ = 4;
constexpr int S_ = 2048;
constexpr int D_ = 1024;
constexpr long BS_ = (long)B_ * S_;     // 8192 rows
constexpr float EPS_ = 1e-5f;

typedef __attribute__((ext_vector_type(8))) short   bfx8;   // MFMA A/B frag (8 bf16)
typedef __attribute__((ext_vector_type(4))) float   fx4;    // MFMA C/D frag
typedef __attribute__((ext_vector_type(8))) unsigned short u16x8;

// ---------- bf16 helpers (bit-level, no header API dependence) ----------
__device__ __forceinline__ unsigned short f2bf(float f) {
    unsigned int x = __float_as_uint(f);
    x = (x + 0x7fffu + ((x >> 16) & 1u)) >> 16;   // RNE
    return (unsigned short)x;
}
__device__ __forceinline__ float bf2f(unsigned short u) {
    return __uint_as_float(((unsigned int)u) << 16);
}

// async global->LDS, 16B per lane. LDS base must be wave-uniform.
__device__ __forceinline__ void gload16(const void* g, void* l) {
    __builtin_amdgcn_global_load_lds(
        (const __attribute__((address_space(1))) unsigned int*)g,
        (__attribute__((address_space(3))) unsigned int*)l,
        16, 0, 0);
}

// =======================================================================
// bf16 MFMA GEMM, m97 structure: 128x128 tile, BK=32, 256 thr (4 waves),
// each wave a 64x64 subtile = 4x4 frags of 16x16, K=32 per MFMA.
// A: [M,K] bf16 row-major. Bt: [N,K] bf16 row-major (i.e. B transposed).
// MODE 0: QKV proj. z in {0,1,2} -> C0=Q bf16, C1=K bf16, C2=V transposed
//         bf16 [b][D][S]; bias = bcat + z*N, added pre-cast.
// MODE 1: scores.  C0 bf16 + z*bC, scaled by alpha.
// MODE 2: PV.      C0 fp32 + z*bC.
// =======================================================================
template<int MODE>
__global__ __launch_bounds__(256)
void mgemm(const unsigned short* __restrict__ A,
           const unsigned short* __restrict__ Bt,
           void* __restrict__ C0, void* __restrict__ C1, void* __restrict__ C2,
           const float* __restrict__ bias,
           int K, int N, long bA, long bB, long bC, float alpha)
{
    const int z = blockIdx.z;
    A  += z * bA;
    Bt += z * bB;

    __shared__ unsigned short As[128 * 32];   // [m][k] 8KB
    __shared__ unsigned short Bs[128 * 32];   // [n][k] 8KB

    const int tid  = threadIdx.x;
    const int lane = tid & 63;
    const int w    = tid >> 6;                // wave 0..3
    const int wr   = w >> 1, wc = w & 1;      // 2x2 wave grid
    const int row0 = blockIdx.x * 128;
    const int col0 = blockIdx.y * 128;

    // staging: slot sl covers rows [16*sl,16*sl+16), LDS base sl*512 ushorts.
    // lane -> row 16*sl + lane/4, k-offset (lane&3)*8   (16B per lane, linear)
    const int lm = lane >> 2;
    const int lk = (lane & 3) * 8;
    const unsigned short* ga0 = A  + (long)(row0 +      w * 16 + lm) * K + lk;
    const unsigned short* ga1 = A  + (long)(row0 + 64 + w * 16 + lm) * K + lk;
    const unsigned short* gb0 = Bt + (long)(col0 +      w * 16 + lm) * K + lk;
    const unsigned short* gb1 = Bt + (long)(col0 + 64 + w * 16 + lm) * K + lk;
    unsigned short* la0 = &As[(w * 16) * 32];        // wave-uniform bases
    unsigned short* la1 = &As[(64 + w * 16) * 32];
    unsigned short* lb0 = &Bs[(w * 16) * 32];
    unsigned short* lb1 = &Bs[(64 + w * 16) * 32];

    fx4 acc[4][4];
#pragma unroll
    for (int i = 0; i < 4; ++i)
#pragma unroll
        for (int j = 0; j < 4; ++j) acc[i][j] = fx4{0.f, 0.f, 0.f, 0.f};

    const int fr = lane & 15;            // frag row (A) / col (B,C)
    const int fk = (lane >> 4) * 8;      // frag k offset

    for (int k0 = 0; k0 < K; k0 += 32) {
        gload16(ga0 + k0, la0);
        gload16(ga1 + k0, la1);
        gload16(gb0 + k0, lb0);
        gload16(gb1 + k0, lb1);
        __syncthreads();                 // drains vmcnt before barrier

        bfx8 af[4], bfr[4];
#pragma unroll
        for (int i = 0; i < 4; ++i)
            af[i] = *(const bfx8*)&As[(wr * 64 + i * 16 + fr) * 32 + fk];
#pragma unroll
        for (int j = 0; j < 4; ++j)
            bfr[j] = *(const bfx8*)&Bs[(wc * 64 + j * 16 + fr) * 32 + fk];
#pragma unroll
        for (int i = 0; i < 4; ++i)
#pragma unroll
            for (int j = 0; j < 4; ++j)
                acc[i][j] = __builtin_amdgcn_mfma_f32_16x16x32_bf16(
                    af[i], bfr[j], acc[i][j], 0, 0, 0);
        __syncthreads();
    }

    // ---- epilogue. C/D frag: col = lane&15, row = (lane>>4)*4 + r  [m89]
    const int r0 = (lane >> 4) * 4;
    if (MODE == 0) {
        const float* bz = bias + z * N;
        if (z < 2) {
            unsigned short* C = (unsigned short*)(z == 0 ? C0 : C1);
#pragma unroll
            for (int i = 0; i < 4; ++i) {
                const int rg0 = row0 + wr * 64 + i * 16 + r0;
#pragma unroll
                for (int j = 0; j < 4; ++j) {
                    const int cg = col0 + wc * 64 + j * 16 + fr;
                    const float bb = bz[cg];
#pragma unroll
                    for (int r = 0; r < 4; ++r)
                        C[(long)(rg0 + r) * N + cg] = f2bf(acc[i][j][r] + bb);
                }
            }
        } else {  // V: store transposed bf16 [b][D][S]
            unsigned short* Vt = (unsigned short*)C2;
#pragma unroll
            for (int i = 0; i < 4; ++i) {
                const int rg0 = row0 + wr * 64 + i * 16 + r0;
                const int b   = rg0 >> 11;          // /2048
                const int s0  = rg0 & 2047;
#pragma unroll
                for (int j = 0; j < 4; ++j) {
                    const int cg = col0 + wc * 64 + j * 16 + fr;
                    const float bb = bz[cg];
                    short4 pk;
                    pk.x = (short)f2bf(acc[i][j][0] + bb);
                    pk.y = (short)f2bf(acc[i][j][1] + bb);
                    pk.z = (short)f2bf(acc[i][j][2] + bb);
                    pk.w = (short)f2bf(acc[i][j][3] + bb);
                    *(short4*)&Vt[(long)b * D_ * S_ + (long)cg * S_ + s0] = pk;
                }
            }
        }
    } else if (MODE == 1) {
        unsigned short* C = (unsigned short*)C0 + z * bC;
#pragma unroll
        for (int i = 0; i < 4; ++i) {
            const int rg0 = row0 + wr * 64 + i * 16 + r0;
#pragma unroll
            for (int j = 0; j < 4; ++j) {
                const int cg = col0 + wc * 64 + j * 16 + fr;
#pragma unroll
                for (int r = 0; r < 4; ++r)
                    C[(long)(rg0 + r) * N + cg] = f2bf(acc[i][j][r] * alpha);
            }
        }
    } else {
        float* C = (float*)C0 + z * bC;
#pragma unroll
        for (int i = 0; i < 4; ++i) {
            const int rg0 = row0 + wr * 64 + i * 16 + r0;
#pragma unroll
            for (int j = 0; j < 4; ++j) {
                const int cg = col0 + wc * 64 + j * 16 + fr;
#pragma unroll
                for (int r = 0; r < 4; ++r)
                    C[(long)(rg0 + r) * N + cg] = acc[i][j][r];
            }
        }
    }
}

// ---------- fp32 -> bf16 cast, 8 elements/thread ----------
__global__ __launch_bounds__(256)
void cast_bf16(const float* __restrict__ in, unsigned short* __restrict__ out)
{
    const long i = (long)blockIdx.x * 256 + threadIdx.x;
    const float4 a = ((const float4*)in)[2 * i];
    const float4 b = ((const float4*)in)[2 * i + 1];
    u16x8 v;
    v[0] = f2bf(a.x); v[1] = f2bf(a.y); v[2] = f2bf(a.z); v[3] = f2bf(a.w);
    v[4] = f2bf(b.x); v[5] = f2bf(b.y); v[6] = f2bf(b.z); v[7] = f2bf(b.w);
    *(u16x8*)(out + i * 8) = v;
}

// ---------- W -> W^T bf16 (3 matrices via z) ----------
__global__ __launch_bounds__(256)
void wtrans_cast(const float* __restrict__ w0, const float* __restrict__ w1,
                 const float* __restrict__ w2, unsigned short* __restrict__ out)
{
    const float* W = blockIdx.z == 0 ? w0 : (blockIdx.z == 1 ? w1 : w2);
    unsigned short* O = out + (long)blockIdx.z * D_ * D_;
    __shared__ float t[32][33];
    const int tx = threadIdx.x & 31, ty = threadIdx.x >> 5;   // ty 0..7
    const int k0 = blockIdx.x * 32, n0 = blockIdx.y * 32;
#pragma unroll
    for (int r = 0; r < 4; ++r)
        t[ty + 8 * r][tx] = W[(long)(k0 + ty + 8 * r) * D_ + n0 + tx];
    __syncthreads();
#pragma unroll
    for (int r = 0; r < 4; ++r)
        O[(long)(n0 + ty + 8 * r) * D_ + k0 + tx] = f2bf(t[tx][ty + 8 * r]);
}

// ---------- row softmax over 2048 bf16, in place ----------
__global__ __launch_bounds__(256)
void softmax_bf16(unsigned short* __restrict__ P, long bStride)
{
    unsigned short* row = P + blockIdx.y * bStride + (long)blockIdx.x * S_;
    const int tid = threadIdx.x, lane = tid & 63, wid = tid >> 6;
    __shared__ float sm[4], ss[4];

    u16x8 v = *(u16x8*)(row + tid * 8);
    float f[8];
#pragma unroll
    for (int i = 0; i < 8; ++i) f[i] = bf2f(v[i]);

    float m = f[0];
#pragma unroll
    for (int i = 1; i < 8; ++i) m = fmaxf(m, f[i]);
#pragma unroll
    for (int o = 1; o < 64; o <<= 1) m = fmaxf(m, __shfl_xor(m, o));
    if (lane == 0) sm[wid] = m;
    __syncthreads();
    m = fmaxf(fmaxf(sm[0], sm[1]), fmaxf(sm[2], sm[3]));

    float s = 0.f;
#pragma unroll
    for (int i = 0; i < 8; ++i) { f[i] = __expf(f[i] - m); s += f[i]; }
#pragma unroll
    for (int o = 1; o < 64; o <<= 1) s += __shfl_xor(s, o);
    if (lane == 0) ss[wid] = s;
    __syncthreads();
    s = ss[0] + ss[1] + ss[2] + ss[3];

    const float inv = 1.0f / s;
#pragma unroll
    for (int i = 0; i < 8; ++i) v[i] = f2bf(f[i] * inv);
    *(u16x8*)(row + tid * 8) = v;
}

// ---------- h = x + attn; out = LN(h)*gamma + beta ----------
__global__ __launch_bounds__(256)
void resid_ln(const float* __restrict__ x, const float* __restrict__ attn,
              const float* __restrict__ gamma, const float* __restrict__ beta,
              float* __restrict__ out)
{
    const long row = blockIdx.x;
    const int tid = threadIdx.x, lane = tid & 63, wid = tid >> 6;
    __shared__ float s1[4], s2[4];

    float4 xv = ((const float4*)(x + row * D_))[tid];
    float4 av = ((const float4*)(attn + row * D_))[tid];
    float4 h;
    h.x = xv.x + av.x; h.y = xv.y + av.y; h.z = xv.z + av.z; h.w = xv.w + av.w;

    float sum = h.x + h.y + h.z + h.w;
#pragma unroll
    for (int o = 1; o < 64; o <<= 1) sum += __shfl_xor(sum, o);
    if (lane == 0) s1[wid] = sum;
    __syncthreads();
    const float mu = (s1[0] + s1[1] + s1[2] + s1[3]) * (1.0f / D_);

    float dx = h.x - mu, dy = h.y - mu, dz = h.z - mu, dw = h.w - mu;
    float sq = dx * dx + dy * dy + dz * dz + dw * dw;
#pragma unroll
    for (int o = 1; o < 64; o <<= 1) sq += __shfl_xor(sq, o);
    if (lane == 0) s2[wid] = sq;
    __syncthreads();
    const float var = (s2[0] + s2[1] + s2[2] + s2[3]) * (1.0f / D_);
    const float r = rsqrtf(var + EPS_);

    float4 g = ((const float4*)gamma)[tid];
    float4 b = ((const float4*)beta)[tid];
    float4 o4;
    o4.x = dx * r * g.x + b.x;
    o4.y = dy * r * g.y + b.y;
    o4.z = dz * r * g.z + b.z;
    o4.w = dw * r * g.w + b.w;
    ((float4*)(out + row * D_))[tid] = o4;
}

extern "C" void kernel_launch(void* const* d_in, const int* in_sizes, int n_in,
                              void* d_out, int out_size, void* d_ws, size_t ws_size,
                              hipStream_t stream) {
    (void)in_sizes; (void)n_in; (void)out_size;
    const float* x     = (const float*)d_in[0];
    const float* Wq    = (const float*)d_in[1];
    const float* bq    = (const float*)d_in[2];
    const float* Wk    = (const float*)d_in[3];
    const float* bk    = (const float*)d_in[4];
    const float* Wv    = (const float*)d_in[5];
    const float* bv    = (const float*)d_in[6];
    const float* gamma = (const float*)d_in[7];
    const float* beta  = (const float*)d_in[8];
    float* out = (float*)d_out;

    // ---- workspace layout (bytes) ----
    const size_t OFF_XB = 0;                                  // x bf16      16.78 MB
    const size_t OFF_WT = OFF_XB + (size_t)BS_ * D_ * 2;      // W^T bf16     6.29 MB
    const size_t OFF_BC = OFF_WT + (size_t)3 * D_ * D_ * 2;   // bias f32     12 KB
    const size_t OFF_QB = OFF_BC + (size_t)3 * D_ * 4;        // Q bf16      16.78 MB
    const size_t OFF_KB = OFF_QB + (size_t)BS_ * D_ * 2;      // K bf16      16.78 MB
    const size_t OFF_VT = OFF_KB + (size_t)BS_ * D_ * 2;      // V^T bf16    16.78 MB
    const size_t OFF_O  = OFF_VT + (size_t)BS_ * D_ * 2;      // attn f32    33.55 MB
    const size_t OFF_P  = OFF_O  + (size_t)BS_ * D_ * 4;      // scores bf16
    const size_t SZ_P1  = (size_t)S_ * S_ * 2;                //  8.39 MB / batch
    const bool full = ws_size >= OFF_P + 4 * SZ_P1;           // 140.5 MB total

    unsigned short* xb  = (unsigned short*)((char*)d_ws + OFF_XB);
    unsigned short* Wtb = (unsigned short*)((char*)d_ws + OFF_WT);
    float*          bc  = (float*)((char*)d_ws + OFF_BC);
    unsigned short* Qb  = (unsigned short*)((char*)d_ws + OFF_QB);
    unsigned short* Kb  = (unsigned short*)((char*)d_ws + OFF_KB);
    unsigned short* Vtb = (unsigned short*)((char*)d_ws + OFF_VT);
    float*          O   = (float*)((char*)d_ws + OFF_O);
    unsigned short* Pb  = (unsigned short*)((char*)d_ws + OFF_P);

    // bias concat (tiny d2d copies, graph-capture safe)
    hipMemcpyAsync(bc,          bq, (size_t)D_ * 4, hipMemcpyDeviceToDevice, stream);
    hipMemcpyAsync(bc + D_,     bk, (size_t)D_ * 4, hipMemcpyDeviceToDevice, stream);
    hipMemcpyAsync(bc + 2 * D_, bv, (size_t)D_ * 4, hipMemcpyDeviceToDevice, stream);

    // casts
    cast_bf16<<<dim3((int)(BS_ * D_ / 8 / 256)), 256, 0, stream>>>(x, xb);
    wtrans_cast<<<dim3(32, 32, 3), 256, 0, stream>>>(Wq, Wk, Wv, Wtb);

    // 1) QKV projection: [8192,1024] @ [1024,1024] -> Q,K bf16; V transposed
    mgemm<0><<<dim3(64, 8, 3), 256, 0, stream>>>(
        xb, Wtb, Qb, Kb, Vtb, bc, D_, D_,
        0L, (long)D_ * D_, 0L, 1.0f);

    // 2) attention, z-batched when workspace allows
    const int  chunk   = full ? 4 : 1;
    const long pstride = full ? (long)S_ * S_ : 0L;
    const long sd      = (long)S_ * D_;
    const long ds      = (long)D_ * S_;
    for (int b0 = 0; b0 < B_; b0 += chunk) {
        // scores = Q @ K^T / 32  -> bf16 [S,S]
        mgemm<1><<<dim3(16, 16, chunk), 256, 0, stream>>>(
            Qb + b0 * sd, Kb + b0 * sd, Pb, nullptr, nullptr, nullptr,
            D_, S_, sd, sd, pstride, 1.0f / 32.0f);
        // softmax rows in place (bf16)
        softmax_bf16<<<dim3(S_, chunk), 256, 0, stream>>>(Pb, pstride);
        // attn_out = P @ V -> fp32 (B^T = V transposed [D,S])
        mgemm<2><<<dim3(16, 8, chunk), 256, 0, stream>>>(
            Pb, Vtb + b0 * ds, O + b0 * sd, nullptr, nullptr, nullptr,
            S_, D_, pstride, ds, sd, 1.0f);
    }

    // 3) residual + LayerNorm (fp32)
    resid_ln<<<dim3((int)BS_), 256, 0, stream>>>(x, O, gamma, beta, out);
}

// Round 4
// 302.704 us; speedup vs baseline: 5.0854x; 1.1118x over previous
//
#include <hip/hip_runtime.h>
#include <math.h>

// Problem constants: B=4, S=2048, D=1024, fp32 in/out
constexpr int B_ = 4;
constexpr int S_ = 2048;
constexpr int D_ = 1024;
constexpr long BS_ = (long)B_ * S_;     // 8192 rows
constexpr float EPS_ = 1e-5f;

typedef __attribute__((ext_vector_type(8))) short   bfx8;   // MFMA A/B frag
typedef __attribute__((ext_vector_type(4))) float   fx4;    // MFMA C/D frag
typedef __attribute__((ext_vector_type(8))) unsigned short u16x8;

__device__ __forceinline__ unsigned short f2bf(float f) {
    unsigned int x = __float_as_uint(f);
    x = (x + 0x7fffu + ((x >> 16) & 1u)) >> 16;   // RNE
    return (unsigned short)x;
}
__device__ __forceinline__ float bf2f(unsigned short u) {
    return __uint_as_float(((unsigned int)u) << 16);
}

// async global->LDS, 16B/lane. LDS base wave-uniform; HW adds lane*16.
__device__ __forceinline__ void gload16(const void* g, void* l) {
    __builtin_amdgcn_global_load_lds(
        (const __attribute__((address_space(1))) unsigned int*)g,
        (__attribute__((address_space(3))) unsigned int*)l,
        16, 0, 0);
}

// =======================================================================
// bf16 MFMA GEMM, 2-phase double-buffered (T3-min recipe):
//   BM=256 x BN=128 tile, BK=32, 512 thr (8 waves, 2Mx4N wave grid),
//   wave owns 128x32 = 8x2 frags of 16x16, mfma_f32_16x16x32_bf16.
//   LDS 48KB (2 x (16KB A + 8KB B)) -> 2 blocks/CU co-resident.
// Schedule per K-tile: STAGE(next) ; ds_read(cur) ; MFMA ; syncthreads.
// A: [M,K] bf16 row-major. Bt: [N,K] bf16 row-major (B transposed).
// MODE 0: QKV proj (z: 0=Q bf16, 1=K bf16, 2=V^T bf16 [b][D][S]), +bias.
// MODE 1: scores -> bf16, scaled by alpha.   MODE 2: PV -> fp32.
// =======================================================================
template<int MODE>
__global__ __launch_bounds__(512, 4)
void mgemm(const unsigned short* __restrict__ A,
           const unsigned short* __restrict__ Bt,
           void* __restrict__ C0, void* __restrict__ C1, void* __restrict__ C2,
           const float* __restrict__ bias,
           int K, int N, long bA, long bB, long bC, float alpha)
{
    const int z = blockIdx.z;
    A  += z * bA;
    Bt += z * bB;

    __shared__ unsigned short As[2][256 * 32];   // [m][k], 16KB each
    __shared__ unsigned short Bs[2][128 * 32];   // [n][k],  8KB each

    const int tid  = threadIdx.x;
    const int lane = tid & 63;
    const int w    = tid >> 6;                // wave 0..7
    const int wr   = w >> 2, wc = w & 3;      // 2x4 wave grid
    const int row0 = blockIdx.x * 256;
    const int col0 = blockIdx.y * 128;

    // ---- staging map: slot s -> row m = s>>2, k-off (s&3)*8 (16B/lane, linear)
    const int s0 = w * 64 + lane;             // 0..511
    const int m0 = s0 >> 2;                   // 0..127
    const int ko = (s0 & 3) * 8;
    const unsigned short* gA0 = A  + (long)(row0 + m0) * K + ko;        // rows 0..127
    const unsigned short* gA1 = A  + (long)(row0 + 128 + m0) * K + ko;  // rows 128..255
    const unsigned short* gB0 = Bt + (long)(col0 + m0) * K + ko;        // n 0..127
    const int lA = w * 512;                   // wave-uniform LDS bases (ushorts)
    const int lB = w * 512;

    fx4 acc[8][2];
#pragma unroll
    for (int i = 0; i < 8; ++i) {
        acc[i][0] = fx4{0.f, 0.f, 0.f, 0.f};
        acc[i][1] = fx4{0.f, 0.f, 0.f, 0.f};
    }

    const int fr = lane & 15;            // frag row (A) / col (B,C)
    const int fk = (lane >> 4) * 8;      // frag k offset
    const int nt = K >> 5;               // K-tiles of 32

    // prologue: stage tile 0, drain, barrier
    gload16(gA0, &As[0][lA]);
    gload16(gA1, &As[0][4096 + lA]);
    gload16(gB0, &Bs[0][lB]);
    __syncthreads();

    for (int t = 0; t < nt; ++t) {
        const int cur = t & 1;
        if (t + 1 < nt) {                // issue NEXT tile before compute
            const int koff = (t + 1) * 32;
            gload16(gA0 + koff, &As[cur ^ 1][lA]);
            gload16(gA1 + koff, &As[cur ^ 1][4096 + lA]);
            gload16(gB0 + koff, &Bs[cur ^ 1][lB]);
        }
        bfx8 af[8], bf[2];
#pragma unroll
        for (int i = 0; i < 8; ++i)
            af[i] = *(const bfx8*)&As[cur][(wr * 128 + i * 16 + fr) * 32 + fk];
#pragma unroll
        for (int j = 0; j < 2; ++j)
            bf[j] = *(const bfx8*)&Bs[cur][(wc * 32 + j * 16 + fr) * 32 + fk];

        __builtin_amdgcn_s_setprio(1);
#pragma unroll
        for (int i = 0; i < 8; ++i)
#pragma unroll
            for (int j = 0; j < 2; ++j)
                acc[i][j] = __builtin_amdgcn_mfma_f32_16x16x32_bf16(
                    af[i], bf[j], acc[i][j], 0, 0, 0);
        __builtin_amdgcn_s_setprio(0);
        __syncthreads();                 // drains prefetch vmcnt + lgkmcnt
    }

    // ---- epilogue. C/D frag: col = lane&15, row = (lane>>4)*4 + r  [m89]
    const int r0 = (lane >> 4) * 4;
    if (MODE == 0) {
        const float* bz = bias + z * N;
        if (z < 2) {
            unsigned short* C = (unsigned short*)(z == 0 ? C0 : C1);
#pragma unroll
            for (int i = 0; i < 8; ++i) {
                const int rg0 = row0 + wr * 128 + i * 16 + r0;
#pragma unroll
                for (int j = 0; j < 2; ++j) {
                    const int cg = col0 + wc * 32 + j * 16 + fr;
                    const float bb = bz[cg];
#pragma unroll
                    for (int r = 0; r < 4; ++r)
                        C[(long)(rg0 + r) * N + cg] = f2bf(acc[i][j][r] + bb);
                }
            }
        } else {  // V: store transposed bf16 [b][D][S]
            unsigned short* Vt = (unsigned short*)C2;
#pragma unroll
            for (int i = 0; i < 8; ++i) {
                const int rg0 = row0 + wr * 128 + i * 16 + r0;
                const int b   = rg0 >> 11;          // /2048 (tiles never straddle)
                const int sv  = rg0 & 2047;
#pragma unroll
                for (int j = 0; j < 2; ++j) {
                    const int cg = col0 + wc * 32 + j * 16 + fr;
                    const float bb = bz[cg];
                    short4 pk;
                    pk.x = (short)f2bf(acc[i][j][0] + bb);
                    pk.y = (short)f2bf(acc[i][j][1] + bb);
                    pk.z = (short)f2bf(acc[i][j][2] + bb);
                    pk.w = (short)f2bf(acc[i][j][3] + bb);
                    *(short4*)&Vt[(long)b * D_ * S_ + (long)cg * S_ + sv] = pk;
                }
            }
        }
    } else if (MODE == 1) {
        unsigned short* C = (unsigned short*)C0 + z * bC;
#pragma unroll
        for (int i = 0; i < 8; ++i) {
            const int rg0 = row0 + wr * 128 + i * 16 + r0;
#pragma unroll
            for (int j = 0; j < 2; ++j) {
                const int cg = col0 + wc * 32 + j * 16 + fr;
#pragma unroll
                for (int r = 0; r < 4; ++r)
                    C[(long)(rg0 + r) * N + cg] = f2bf(acc[i][j][r] * alpha);
            }
        }
    } else {
        float* C = (float*)C0 + z * bC;
#pragma unroll
        for (int i = 0; i < 8; ++i) {
            const int rg0 = row0 + wr * 128 + i * 16 + r0;
#pragma unroll
            for (int j = 0; j < 2; ++j) {
                const int cg = col0 + wc * 32 + j * 16 + fr;
#pragma unroll
                for (int r = 0; r < 4; ++r)
                    C[(long)(rg0 + r) * N + cg] = acc[i][j][r];
            }
        }
    }
}

// ---------- fp32 -> bf16 cast, 8 elements/thread ----------
__global__ __launch_bounds__(256)
void cast_bf16(const float* __restrict__ in, unsigned short* __restrict__ out)
{
    const long i = (long)blockIdx.x * 256 + threadIdx.x;
    const float4 a = ((const float4*)in)[2 * i];
    const float4 b = ((const float4*)in)[2 * i + 1];
    u16x8 v;
    v[0] = f2bf(a.x); v[1] = f2bf(a.y); v[2] = f2bf(a.z); v[3] = f2bf(a.w);
    v[4] = f2bf(b.x); v[5] = f2bf(b.y); v[6] = f2bf(b.z); v[7] = f2bf(b.w);
    *(u16x8*)(out + i * 8) = v;
}

// ---------- W -> W^T bf16 (3 matrices via z) ----------
__global__ __launch_bounds__(256)
void wtrans_cast(const float* __restrict__ w0, const float* __restrict__ w1,
                 const float* __restrict__ w2, unsigned short* __restrict__ out)
{
    const float* W = blockIdx.z == 0 ? w0 : (blockIdx.z == 1 ? w1 : w2);
    unsigned short* O = out + (long)blockIdx.z * D_ * D_;
    __shared__ float t[32][33];
    const int tx = threadIdx.x & 31, ty = threadIdx.x >> 5;   // ty 0..7
    const int k0 = blockIdx.x * 32, n0 = blockIdx.y * 32;
#pragma unroll
    for (int r = 0; r < 4; ++r)
        t[ty + 8 * r][tx] = W[(long)(k0 + ty + 8 * r) * D_ + n0 + tx];
    __syncthreads();
#pragma unroll
    for (int r = 0; r < 4; ++r)
        O[(long)(n0 + ty + 8 * r) * D_ + k0 + tx] = f2bf(t[tx][ty + 8 * r]);
}

// ---------- row softmax over 2048 bf16, in place ----------
__global__ __launch_bounds__(256)
void softmax_bf16(unsigned short* __restrict__ P, long bStride)
{
    unsigned short* row = P + blockIdx.y * bStride + (long)blockIdx.x * S_;
    const int tid = threadIdx.x, lane = tid & 63, wid = tid >> 6;
    __shared__ float sm[4], ss[4];

    u16x8 v = *(u16x8*)(row + tid * 8);
    float f[8];
#pragma unroll
    for (int i = 0; i < 8; ++i) f[i] = bf2f(v[i]);

    float m = f[0];
#pragma unroll
    for (int i = 1; i < 8; ++i) m = fmaxf(m, f[i]);
#pragma unroll
    for (int o = 1; o < 64; o <<= 1) m = fmaxf(m, __shfl_xor(m, o));
    if (lane == 0) sm[wid] = m;
    __syncthreads();
    m = fmaxf(fmaxf(sm[0], sm[1]), fmaxf(sm[2], sm[3]));

    float s = 0.f;
#pragma unroll
    for (int i = 0; i < 8; ++i) { f[i] = __expf(f[i] - m); s += f[i]; }
#pragma unroll
    for (int o = 1; o < 64; o <<= 1) s += __shfl_xor(s, o);
    if (lane == 0) ss[wid] = s;
    __syncthreads();
    s = ss[0] + ss[1] + ss[2] + ss[3];

    const float inv = 1.0f / s;
#pragma unroll
    for (int i = 0; i < 8; ++i) v[i] = f2bf(f[i] * inv);
    *(u16x8*)(row + tid * 8) = v;
}

// ---------- h = x + attn; out = LN(h)*gamma + beta ----------
__global__ __launch_bounds__(256)
void resid_ln(const float* __restrict__ x, const float* __restrict__ attn,
              const float* __restrict__ gamma, const float* __restrict__ beta,
              float* __restrict__ out)
{
    const long row = blockIdx.x;
    const int tid = threadIdx.x, lane = tid & 63, wid = tid >> 6;
    __shared__ float s1[4], s2[4];

    float4 xv = ((const float4*)(x + row * D_))[tid];
    float4 av = ((const float4*)(attn + row * D_))[tid];
    float4 h;
    h.x = xv.x + av.x; h.y = xv.y + av.y; h.z = xv.z + av.z; h.w = xv.w + av.w;

    float sum = h.x + h.y + h.z + h.w;
#pragma unroll
    for (int o = 1; o < 64; o <<= 1) sum += __shfl_xor(sum, o);
    if (lane == 0) s1[wid] = sum;
    __syncthreads();
    const float mu = (s1[0] + s1[1] + s1[2] + s1[3]) * (1.0f / D_);

    float dx = h.x - mu, dy = h.y - mu, dz = h.z - mu, dw = h.w - mu;
    float sq = dx * dx + dy * dy + dz * dz + dw * dw;
#pragma unroll
    for (int o = 1; o < 64; o <<= 1) sq += __shfl_xor(sq, o);
    if (lane == 0) s2[wid] = sq;
    __syncthreads();
    const float var = (s2[0] + s2[1] + s2[2] + s2[3]) * (1.0f / D_);
    const float r = rsqrtf(var + EPS_);

    float4 g = ((const float4*)gamma)[tid];
    float4 b = ((const float4*)beta)[tid];
    float4 o4;
    o4.x = dx * r * g.x + b.x;
    o4.y = dy * r * g.y + b.y;
    o4.z = dz * r * g.z + b.z;
    o4.w = dw * r * g.w + b.w;
    ((float4*)(out + row * D_))[tid] = o4;
}

extern "C" void kernel_launch(void* const* d_in, const int* in_sizes, int n_in,
                              void* d_out, int out_size, void* d_ws, size_t ws_size,
                              hipStream_t stream) {
    (void)in_sizes; (void)n_in; (void)out_size;
    const float* x     = (const float*)d_in[0];
    const float* Wq    = (const float*)d_in[1];
    const float* bq    = (const float*)d_in[2];
    const float* Wk    = (const float*)d_in[3];
    const float* bk    = (const float*)d_in[4];
    const float* Wv    = (const float*)d_in[5];
    const float* bv    = (const float*)d_in[6];
    const float* gamma = (const float*)d_in[7];
    const float* beta  = (const float*)d_in[8];
    float* out = (float*)d_out;

    // ---- workspace layout (bytes) ----
    const size_t OFF_XB = 0;                                  // x bf16      16.78 MB
    const size_t OFF_WT = OFF_XB + (size_t)BS_ * D_ * 2;      // W^T bf16     6.29 MB
    const size_t OFF_BC = OFF_WT + (size_t)3 * D_ * D_ * 2;   // bias f32     12 KB
    const size_t OFF_QB = OFF_BC + (size_t)3 * D_ * 4;        // Q bf16      16.78 MB
    const size_t OFF_KB = OFF_QB + (size_t)BS_ * D_ * 2;      // K bf16      16.78 MB
    const size_t OFF_VT = OFF_KB + (size_t)BS_ * D_ * 2;      // V^T bf16    16.78 MB
    const size_t OFF_O  = OFF_VT + (size_t)BS_ * D_ * 2;      // attn f32    33.55 MB
    const size_t OFF_P  = OFF_O  + (size_t)BS_ * D_ * 4;      // scores bf16
    const size_t SZ_P1  = (size_t)S_ * S_ * 2;                //  8.39 MB / batch
    const bool full = ws_size >= OFF_P + 4 * SZ_P1;           // 140.5 MB total

    unsigned short* xb  = (unsigned short*)((char*)d_ws + OFF_XB);
    unsigned short* Wtb = (unsigned short*)((char*)d_ws + OFF_WT);
    float*          bc  = (float*)((char*)d_ws + OFF_BC);
    unsigned short* Qb  = (unsigned short*)((char*)d_ws + OFF_QB);
    unsigned short* Kb  = (unsigned short*)((char*)d_ws + OFF_KB);
    unsigned short* Vtb = (unsigned short*)((char*)d_ws + OFF_VT);
    float*          O   = (float*)((char*)d_ws + OFF_O);
    unsigned short* Pb  = (unsigned short*)((char*)d_ws + OFF_P);

    // bias concat (tiny d2d copies, graph-capture safe)
    hipMemcpyAsync(bc,          bq, (size_t)D_ * 4, hipMemcpyDeviceToDevice, stream);
    hipMemcpyAsync(bc + D_,     bk, (size_t)D_ * 4, hipMemcpyDeviceToDevice, stream);
    hipMemcpyAsync(bc + 2 * D_, bv, (size_t)D_ * 4, hipMemcpyDeviceToDevice, stream);

    // casts
    cast_bf16<<<dim3((int)(BS_ * D_ / 8 / 256)), 256, 0, stream>>>(x, xb);
    wtrans_cast<<<dim3(32, 32, 3), 256, 0, stream>>>(Wq, Wk, Wv, Wtb);

    // 1) QKV projection: [8192,1024] @ [1024,1024] -> Q,K bf16; V transposed
    mgemm<0><<<dim3(32, 8, 3), 512, 0, stream>>>(
        xb, Wtb, Qb, Kb, Vtb, bc, D_, D_,
        0L, (long)D_ * D_, 0L, 1.0f);

    // 2) attention, z-batched when workspace allows
    const int  chunk   = full ? 4 : 1;
    const long pstride = full ? (long)S_ * S_ : 0L;
    const long sd      = (long)S_ * D_;
    const long ds      = (long)D_ * S_;
    for (int b0 = 0; b0 < B_; b0 += chunk) {
        // scores = Q @ K^T / 32  -> bf16 [S,S]
        mgemm<1><<<dim3(8, 16, chunk), 512, 0, stream>>>(
            Qb + b0 * sd, Kb + b0 * sd, Pb, nullptr, nullptr, nullptr,
            D_, S_, sd, sd, pstride, 1.0f / 32.0f);
        // softmax rows in place (bf16)
        softmax_bf16<<<dim3(S_, chunk), 256, 0, stream>>>(Pb, pstride);
        // attn_out = P @ V -> fp32 (B^T = V transposed [D,S])
        mgemm<2><<<dim3(8, 8, chunk), 512, 0, stream>>>(
            Pb, Vtb + b0 * ds, O + b0 * sd, nullptr, nullptr, nullptr,
            S_, D_, pstride, ds, sd, 1.0f);
    }

    // 3) residual + LayerNorm (fp32)
    resid_ln<<<dim3((int)BS_), 256, 0, stream>>>(x, O, gamma, beta, out);
}